// Round 1
// baseline (204.578 us; speedup 1.0000x reference)
//
#include <hip/hip_runtime.h>

#define EMBED 256
#define NUM_DEPTH 128
#define CT_STRIDE 136   // 128 + 8 pad: keeps 16B alignment (272B rows), breaks pow-2 bank stride
#define SEG 128         // tap entries per (bin, producer-block) segment (expected ~32, +17 sigma headroom)
#define BPQ 64          // binning blocks per q-block: (128 q * 128 d) / 256 threads

typedef __attribute__((ext_vector_type(8))) short bf16x8;
typedef __attribute__((ext_vector_type(4))) float f32x4;

__device__ __forceinline__ unsigned short f2b(float f) {
    union { float f; unsigned u; } c; c.f = f;
    unsigned u = c.u;
    u += 0x7fffu + ((u >> 16) & 1u);   // RNE to bf16
    return (unsigned short)(u >> 16);
}
__device__ __forceinline__ float b2f(unsigned short h) {
    union { unsigned u; float f; } c; c.u = ((unsigned)h) << 16;
    return c.f;
}

// ---------------- Phase 1: cvt(fp32->bf16) + tap binning + out=identity ----------------
// Blocks [0, cvtBlocks): convert key/value. Blocks [cvtBlocks, +nq*128/256): each owns
// 256 l-values (2 queries) of ONE q-block; bins the <=4 valid bilinear taps per l into
// per-(q-block, p-block) segments. Deterministic segment ownership (bb & 63) means no
// global atomics and no pre-zeroing: counts are fully rewritten every run (poison-safe).
__global__ __launch_bounds__(256) void prep_kernel(
    const float4* __restrict__ key, const float4* __restrict__ val,
    ushort4* __restrict__ kb, ushort4* __restrict__ vb, int n4, int cvtBlocks,
    const float* __restrict__ identity, const float* __restrict__ ref3d,
    const int* __restrict__ spatial, float* __restrict__ out,
    unsigned* __restrict__ cnts, unsigned* __restrict__ gent, int NB, int nv)
{
    const int tid = threadIdx.x;
    if ((int)blockIdx.x < cvtBlocks) {
        int i = blockIdx.x * 256 + tid;
        if (i < n4) {
            float4 a = key[i];
            float4 b = val[i];
            kb[i] = make_ushort4(f2b(a.x), f2b(a.y), f2b(a.z), f2b(a.w));
            vb[i] = make_ushort4(f2b(b.x), f2b(b.y), f2b(b.z), f2b(b.w));
        }
        return;
    }

    __shared__ unsigned cnt[32];
    if (tid < 32) cnt[tid] = 0;
    __syncthreads();

    const int bb = blockIdx.x - cvtBlocks;
    const int l  = bb * 256 + tid;          // global (q,d) pair index
    out[l] = identity[l];                   // init output (atomics accumulate on top)

    const int Hs = spatial[0], Ws = spatial[1];
    const float2 r2 = reinterpret_cast<const float2*>(ref3d)[l];
    const float px = r2.x * (float)Ws - 0.5f;
    const float py = r2.y * (float)Hs - 0.5f;
    const float x0f = floorf(px), y0f = floorf(py);
    const int ix0 = (int)x0f, iy0 = (int)y0f;

    int pbt[4]; unsigned slot[4];
    #pragma unroll
    for (int t = 0; t < 4; ++t) {
        const int ix = ix0 + (t & 1);
        const int iy = iy0 + (t >> 1);
        pbt[t] = -1;
        if (ix >= 0 && ix < Ws && iy >= 0 && iy < Hs) {
            const int p = iy * Ws + ix;     // pixel == column of D
            if (p < nv) {
                pbt[t]  = p >> 7;           // 128-column GEMM block owning this tap
                slot[t] = atomicAdd(&cnt[pbt[t]], 1u);   // LDS atomic: slot in our segment
            }
        }
    }
    __syncthreads();

    const int qb  = bb >> 6;                // q-block (64 binning blocks per q-block)
    const int blk = bb & 63;                // our segment id within each bin
    if (tid < NB) cnts[((size_t)qb * NB + tid) * BPQ + blk] = cnt[tid];  // always written

    #pragma unroll
    for (int t = 0; t < 4; ++t)
        if (pbt[t] >= 0 && slot[t] < SEG)
            gent[(((size_t)qb * NB + pbt[t]) * BPQ + blk) * SEG + slot[t]] =
                ((unsigned)l << 2) | (unsigned)t;
}

// ---------------- Phase 2: fused NT-GEMM tile + tap scatter ----------------
// 128x128 tile per block, 256 threads (4 waves 2x2), 16x16x32 bf16 MFMA,
// global_load_lds width-16 staging (m97 structure). Epilogue keeps the C-tile
// in LDS (bf16) and directly consumes this bin's tap list: one ds_read + one
// atomicAdd(out) per tap. D is never written to global memory.
__global__ __launch_bounds__(256) void gemm_scatter(
    const unsigned short* __restrict__ A,   // key bf16 [M][256]
    const unsigned short* __restrict__ B,   // value bf16 [N][256]
    const float* __restrict__ ref3d,
    const int* __restrict__ spatial,
    float* __restrict__ out,
    const unsigned* __restrict__ cnts, const unsigned* __restrict__ gent, int NB)
{
    __shared__ __align__(16) unsigned short Ct[128 * CT_STRIDE];  // 34816 B
    unsigned short* As = Ct;              // [128*32] = 8 KB (aliased; dead after K-loop)
    unsigned short* Bs = Ct + 128 * 32;   // next 8 KB

    const int m0 = blockIdx.y * 128;      // q-range
    const int n0 = blockIdx.x * 128;      // p-range
    const int tid  = threadIdx.x;
    const int lane = tid & 63;
    const int wave = tid >> 6;
    const int wm = (wave & 1) * 64;
    const int wn = (wave >> 1) * 64;

    f32x4 acc[4][4] = {};

    const int srow = lane >> 2;
    const int scol = (lane & 3) * 8;
    const int k8 = (lane >> 4) * 8;
    const int fm = lane & 15;

    for (int kt = 0; kt < EMBED; kt += 32) {
        #pragma unroll
        for (int t = 0; t < 2; ++t) {
            const int c = wave * 2 + t;
            const int row = c * 16 + srow;
            const unsigned short* ga = A + (size_t)(m0 + row) * EMBED + kt + scol;
            const unsigned short* gb = B + (size_t)(n0 + row) * EMBED + kt + scol;
            __builtin_amdgcn_global_load_lds(
                (const __attribute__((address_space(1))) void*)ga,
                (__attribute__((address_space(3))) void*)(As + c * 512), 16, 0, 0);
            __builtin_amdgcn_global_load_lds(
                (const __attribute__((address_space(1))) void*)gb,
                (__attribute__((address_space(3))) void*)(Bs + c * 512), 16, 0, 0);
        }
        __syncthreads();

        bf16x8 af[4], bfr[4];
        #pragma unroll
        for (int i = 0; i < 4; ++i) {
            af[i]  = *(const bf16x8*)(As + (wm + i * 16 + fm) * 32 + k8);
            bfr[i] = *(const bf16x8*)(Bs + (wn + i * 16 + fm) * 32 + k8);
        }
        #pragma unroll
        for (int i = 0; i < 4; ++i)
            #pragma unroll
            for (int j = 0; j < 4; ++j)
                acc[i][j] = __builtin_amdgcn_mfma_f32_16x16x32_bf16(af[i], bfr[j], acc[i][j], 0, 0, 0);
        __syncthreads();   // also makes As/Bs dead -> Ct reuse below is safe
    }

    // ---- fragments -> Ct (bf16). C/D layout: col=lane&15, row=(lane>>4)*4+r ----
    const int col = lane & 15;
    const int rbase = (lane >> 4) * 4;
    #pragma unroll
    for (int i = 0; i < 4; ++i)
        #pragma unroll
        for (int j = 0; j < 4; ++j) {
            const int rr = wm + i * 16 + rbase;
            const int cc = wn + j * 16 + col;
            #pragma unroll
            for (int r = 0; r < 4; ++r)
                Ct[(rr + r) * CT_STRIDE + cc] = f2b(acc[i][j][r]);
        }
    __syncthreads();

    // ---- consume this bin's tap list ----
    const size_t bin = (size_t)blockIdx.y * NB + blockIdx.x;
    const unsigned* __restrict__ cseg = cnts + bin * BPQ;
    const unsigned* __restrict__ eseg = gent + bin * BPQ * SEG;
    const int Hs = spatial[0], Ws = spatial[1];

    const int seg = tid & 63;              // 4 threads cooperate per segment
    const unsigned c = min(cseg[seg], (unsigned)SEG);
    for (unsigned i = (unsigned)(tid >> 6); i < c; i += 4) {
        const unsigned e = eseg[seg * SEG + i];
        const int l = (int)(e >> 2);
        const int t = (int)(e & 3u);
        const float2 r2 = reinterpret_cast<const float2*>(ref3d)[l];
        const float px = r2.x * (float)Ws - 0.5f;
        const float py = r2.y * (float)Hs - 0.5f;
        const float x0f = floorf(px), y0f = floorf(py);
        const float fx = px - x0f, fy = py - y0f;
        const float wx = (t & 1) ? fx : 1.0f - fx;
        const float wy = (t & 2) ? fy : 1.0f - fy;
        const int ix = (int)x0f + (t & 1);
        const int iy = (int)y0f + ((t >> 1) & 1);
        const int p = iy * Ws + ix;
        const float v = b2f(Ct[((l >> 7) & 127) * CT_STRIDE + (p & 127)]);
        atomicAdd(out + l, wx * wy * v * 0.0625f);   // 1/sqrt(256) = 1/16
    }
}

// ---------------- Fallback (round-1 direct kernel) ----------------
__global__ __launch_bounds__(256) void uv_direct_kernel(
    const float* __restrict__ key, const float* __restrict__ value,
    const float* __restrict__ identity, const float* __restrict__ ref3d,
    const int* __restrict__ spatial, float* __restrict__ out)
{
    const int q = blockIdx.x;
    const int tid = threadIdx.x;
    const int lane = tid & 63;
    const int wave = tid >> 6;
    const int H = spatial[0], W = spatial[1];
    const int row4 = EMBED / 4;
    const float4 k4 = reinterpret_cast<const float4*>(key + (size_t)q * EMBED)[lane];
    const float4* __restrict__ v4 = reinterpret_cast<const float4*>(value);
    for (int d = wave; d < NUM_DEPTH; d += 4) {
        const int l = q * NUM_DEPTH + d;
        const float rx = ref3d[2 * l], ry = ref3d[2 * l + 1];
        const float px = rx * (float)W - 0.5f, py = ry * (float)H - 0.5f;
        const float x0f = floorf(px), y0f = floorf(py);
        const int ix0 = (int)x0f, iy0 = (int)y0f, ix1 = ix0 + 1, iy1 = iy0 + 1;
        const float wx1 = px - x0f, wx0 = 1.f - wx1, wy1 = py - y0f, wy0 = 1.f - wy1;
        float4 acc = make_float4(0.f, 0.f, 0.f, 0.f);
        #define TAP(IY, IX, WGT) \
            if ((IY) >= 0 && (IY) < H && (IX) >= 0 && (IX) < W) { \
                const float w_ = (WGT); \
                const float4 t = v4[(size_t)((IY) * W + (IX)) * row4 + lane]; \
                acc.x = fmaf(w_, t.x, acc.x); acc.y = fmaf(w_, t.y, acc.y); \
                acc.z = fmaf(w_, t.z, acc.z); acc.w = fmaf(w_, t.w, acc.w); }
        TAP(iy0, ix0, wy0 * wx0) TAP(iy0, ix1, wy0 * wx1)
        TAP(iy1, ix0, wy1 * wx0) TAP(iy1, ix1, wy1 * wx1)
        #undef TAP
        float partial = acc.x * k4.x + acc.y * k4.y + acc.z * k4.z + acc.w * k4.w;
        #pragma unroll
        for (int off = 32; off > 0; off >>= 1) partial += __shfl_xor(partial, off, 64);
        if (lane == 0) out[l] = fmaf(partial, 0.0625f, identity[l]);
    }
}

extern "C" void kernel_launch(void* const* d_in, const int* in_sizes, int n_in,
                              void* d_out, int out_size, void* d_ws, size_t ws_size,
                              hipStream_t stream) {
    // inputs: 0 query(unused) 1 key 2 value 3 identity 4 ref_3d 5 spatial 6 W_attn(unused) 7 b_attn(unused)
    const float* key      = (const float*)d_in[1];
    const float* value    = (const float*)d_in[2];
    const float* identity = (const float*)d_in[3];
    const float* ref3d    = (const float*)d_in[4];
    const int*   spatial  = (const int*)d_in[5];
    float* out = (float*)d_out;

    const int nq = in_sizes[3] / NUM_DEPTH;   // 4096 queries
    const int nv = in_sizes[1] / EMBED;       // 4096 pixels (= H*W)

    const int MB = nq >> 7, NB = nv >> 7;
    const size_t kb_bytes  = (size_t)nq * EMBED * sizeof(unsigned short);
    const size_t vb_bytes  = (size_t)nv * EMBED * sizeof(unsigned short);
    const size_t cnt_bytes = (size_t)MB * NB * BPQ * sizeof(unsigned);
    const size_t ent_bytes = (size_t)MB * NB * BPQ * SEG * sizeof(unsigned);
    const size_t need = kb_bytes + vb_bytes + cnt_bytes + ent_bytes;

    if (ws_size < need || (nq % 128) || (nv % 128) || nv > 4096 || nq != nv) {
        uv_direct_kernel<<<nq, 256, 0, stream>>>(key, value, identity, ref3d, spatial, out);
        return;
    }

    unsigned short* kb = (unsigned short*)d_ws;
    unsigned short* vb = (unsigned short*)((char*)d_ws + kb_bytes);
    unsigned* cnts = (unsigned*)((char*)d_ws + kb_bytes + vb_bytes);
    unsigned* gent = cnts + (size_t)MB * NB * BPQ;

    // Phase 1: convert key/value to bf16 + bin taps + out = identity
    const int n4 = nq * EMBED / 4;
    const int cvtBlocks = (n4 + 255) / 256;
    const int binBlocks = nq * NUM_DEPTH / 256;
    prep_kernel<<<cvtBlocks + binBlocks, 256, 0, stream>>>(
        (const float4*)key, (const float4*)value, (ushort4*)kb, (ushort4*)vb,
        n4, cvtBlocks, identity, ref3d, spatial, out, cnts, gent, NB, nv);

    // Phase 2: tiled D = key.value^T with in-LDS tap scatter (no D materialization)
    dim3 grid(NB, MB);
    gemm_scatter<<<grid, 256, 0, stream>>>(kb, vb, ref3d, spatial, out, cnts, gent, NB);
}

// Round 2
// 107.794 us; speedup vs baseline: 1.8979x; 1.8979x over previous
//
#include <hip/hip_runtime.h>

#define EMBED 256
#define NUM_DEPTH 128
#define CT_STRIDE 136   // 128 + 8 pad: keeps 16B alignment (272B rows), breaks pow-2 bank stride
#define SEG 64          // entries per (bin, producer-block) segment (mean ~16, +8 sigma headroom)
#define BPQ 64          // binning blocks per q-block: (128 q * 128 d) / 256 threads

typedef __attribute__((ext_vector_type(8))) short bf16x8;
typedef __attribute__((ext_vector_type(4))) float f32x4;
typedef __attribute__((ext_vector_type(2))) _Float16 f16x2;

union HWPack { unsigned u; f16x2 h; };

__device__ __forceinline__ unsigned short f2b(float f) {
    union { float f; unsigned u; } c; c.f = f;
    unsigned u = c.u;
    u += 0x7fffu + ((u >> 16) & 1u);   // RNE to bf16
    return (unsigned short)(u >> 16);
}
__device__ __forceinline__ float b2f(unsigned short h) {
    union { unsigned u; float f; } c; c.u = ((unsigned)h) << 16;
    return c.f;
}

// ---------------- Phase 1: cvt(fp32->bf16) + tap binning (weights precomputed) --------
// Blocks [0, cvtBlocks): convert key/value. Blocks [cvtBlocks, +nq/2): each owns 256
// l-values (2 queries) of ONE q-block. Per l, per valid image row iy: one 8B entry
// {meta = l<<9 | slot<<7 | col, half2{w0,w1}} binned to the p-block owning that row's
// taps. slot = (row parity)*2 + (col parity) makes every pp[slot][l] single-writer ->
// the consumer needs NO atomics. Deterministic per-producer-block segments mean no
// global atomics in prep and no memset (counts fully rewritten each run: poison-safe).
__global__ __launch_bounds__(256) void prep_kernel(
    const float4* __restrict__ key, const float4* __restrict__ val,
    ushort4* __restrict__ kb, ushort4* __restrict__ vb, int n4, int cvtBlocks,
    const float* __restrict__ ref3d, const int* __restrict__ spatial,
    float* __restrict__ pp,                 // [4][L] partial sums, zeroed here
    unsigned* __restrict__ cnts,            // [qb][nb][BPQ]
    uint2* __restrict__ gent,               // [qb][nb][BPQ][SEG]
    int NB, int nv, int L)
{
    const int tid = threadIdx.x;
    if ((int)blockIdx.x < cvtBlocks) {
        int i = blockIdx.x * 256 + tid;
        if (i < n4) {
            float4 a = key[i];
            float4 b = val[i];
            kb[i] = make_ushort4(f2b(a.x), f2b(a.y), f2b(a.z), f2b(a.w));
            vb[i] = make_ushort4(f2b(b.x), f2b(b.y), f2b(b.z), f2b(b.w));
        }
        return;
    }

    __shared__ unsigned cnt[32];
    if (tid < 32) cnt[tid] = 0;
    __syncthreads();

    const int bb = blockIdx.x - cvtBlocks;
    const int l  = bb * 256 + tid;          // global (q,d) pair index
    // zero the 4 partial-sum slots (consumer overwrites the ones it owns)
    pp[l] = 0.f; pp[L + l] = 0.f; pp[2 * L + l] = 0.f; pp[3 * L + l] = 0.f;

    const int Hs = spatial[0], Ws = spatial[1];
    const float2 r2 = reinterpret_cast<const float2*>(ref3d)[l];
    const float px = r2.x * (float)Ws - 0.5f;
    const float py = r2.y * (float)Hs - 0.5f;
    const float x0f = floorf(px), y0f = floorf(py);
    const int ix0 = (int)x0f, iy0 = (int)y0f;
    const float wx1 = px - x0f, wx0 = 1.0f - wx1;
    const float wy1 = py - y0f, wy0 = 1.0f - wy1;

    const int qb  = bb >> 6;                // q-block (64 binning blocks per q-block)
    const int blk = bb & 63;                // our segment id within each bin

    #pragma unroll
    for (int s = 0; s < 2; ++s) {
        const int iy = iy0 + s;
        if (iy < 0 || iy >= Hs) continue;
        const float wy = s ? wy1 : wy0;
        const bool v0 = (ix0 >= 0) && (ix0 < Ws);
        const bool v1 = (ix0 + 1 >= 0) && (ix0 + 1 < Ws);
        if (!v0 && !v1) continue;
        const int cix = v0 ? ix0 : (ix0 + 1);        // first valid column
        const float w0 = v0 ? wy * wx0 : wy * wx1;
        const float w1 = (v0 && v1) ? wy * wx1 : 0.f;
        const int p0  = iy * Ws + cix;
        const int nb0 = p0 >> 7;
        const int nb1 = (p0 + (w1 != 0.f ? 1 : 0)) >> 7;
        if (nb0 == nb1) {
            // both taps in one p-block: one pair entry
            HWPack hw; hw.h[0] = (_Float16)w0; hw.h[1] = (_Float16)w1;
            const unsigned slot = (unsigned)(s * 2 + (cix & 1));
            const unsigned meta = ((unsigned)l << 9) | (slot << 7) | (unsigned)(p0 & 127);
            const unsigned idx = atomicAdd(&cnt[nb0], 1u);   // LDS atomic
            if (idx < SEG)
                gent[(((size_t)qb * NB + nb0) * BPQ + blk) * SEG + idx] =
                    make_uint2(meta, hw.u);
        } else {
            // taps straddle a p-block boundary (only possible for W >= 256): 2 singles
            HWPack ha; ha.h[0] = (_Float16)w0; ha.h[1] = (_Float16)0.f;
            unsigned slot = (unsigned)(s * 2 + (cix & 1));
            unsigned meta = ((unsigned)l << 9) | (slot << 7) | (unsigned)(p0 & 127);
            unsigned idx = atomicAdd(&cnt[nb0], 1u);
            if (idx < SEG)
                gent[(((size_t)qb * NB + nb0) * BPQ + blk) * SEG + idx] =
                    make_uint2(meta, ha.u);
            HWPack hb; hb.h[0] = (_Float16)w1; hb.h[1] = (_Float16)0.f;
            slot = (unsigned)(s * 2 + ((cix + 1) & 1));
            meta = ((unsigned)l << 9) | (slot << 7) | (unsigned)((p0 + 1) & 127);
            idx = atomicAdd(&cnt[nb1], 1u);
            if (idx < SEG)
                gent[(((size_t)qb * NB + nb1) * BPQ + blk) * SEG + idx] =
                    make_uint2(meta, hb.u);
        }
    }
    __syncthreads();
    if (tid < NB) cnts[((size_t)qb * NB + tid) * BPQ + blk] = cnt[tid];  // always written
}

// ---------------- Phase 2: fused NT-GEMM tile + atomic-free tap scatter ----------------
// 128x128 tile per block, 256 threads (4 waves 2x2), 16x16x32 bf16 MFMA,
// global_load_lds width-16 staging (m97 structure). Epilogue keeps the C-tile in LDS
// (bf16) and consumes this bin's precomputed tap entries: one 8B load + two ds_reads +
// one plain store per entry. No ref3d reads, no atomics, no D materialization.
__global__ __launch_bounds__(256) void gemm_scatter(
    const unsigned short* __restrict__ A,   // key bf16 [M][256]
    const unsigned short* __restrict__ B,   // value bf16 [N][256]
    float* __restrict__ pp,                 // [4][L]
    const unsigned* __restrict__ cnts, const uint2* __restrict__ gent,
    int NB, int L)
{
    __shared__ __align__(16) unsigned short Ct[128 * CT_STRIDE];  // 34816 B
    unsigned short* As = Ct;              // [128*32] = 8 KB (aliased; dead after K-loop)
    unsigned short* Bs = Ct + 128 * 32;   // next 8 KB

    const int m0 = blockIdx.y * 128;      // q-range
    const int n0 = blockIdx.x * 128;      // p-range
    const int tid  = threadIdx.x;
    const int lane = tid & 63;
    const int wave = tid >> 6;
    const int wm = (wave & 1) * 64;
    const int wn = (wave >> 1) * 64;

    f32x4 acc[4][4] = {};

    const int srow = lane >> 2;
    const int scol = (lane & 3) * 8;
    const int k8 = (lane >> 4) * 8;
    const int fm = lane & 15;

    for (int kt = 0; kt < EMBED; kt += 32) {
        #pragma unroll
        for (int t = 0; t < 2; ++t) {
            const int c = wave * 2 + t;
            const int row = c * 16 + srow;
            const unsigned short* ga = A + (size_t)(m0 + row) * EMBED + kt + scol;
            const unsigned short* gb = B + (size_t)(n0 + row) * EMBED + kt + scol;
            __builtin_amdgcn_global_load_lds(
                (const __attribute__((address_space(1))) void*)ga,
                (__attribute__((address_space(3))) void*)(As + c * 512), 16, 0, 0);
            __builtin_amdgcn_global_load_lds(
                (const __attribute__((address_space(1))) void*)gb,
                (__attribute__((address_space(3))) void*)(Bs + c * 512), 16, 0, 0);
        }
        __syncthreads();

        bf16x8 af[4], bfr[4];
        #pragma unroll
        for (int i = 0; i < 4; ++i) {
            af[i]  = *(const bf16x8*)(As + (wm + i * 16 + fm) * 32 + k8);
            bfr[i] = *(const bf16x8*)(Bs + (wn + i * 16 + fm) * 32 + k8);
        }
        #pragma unroll
        for (int i = 0; i < 4; ++i)
            #pragma unroll
            for (int j = 0; j < 4; ++j)
                acc[i][j] = __builtin_amdgcn_mfma_f32_16x16x32_bf16(af[i], bfr[j], acc[i][j], 0, 0, 0);
        __syncthreads();   // also makes As/Bs dead -> Ct reuse below is safe
    }

    // ---- fragments -> Ct (bf16). C/D layout: col=lane&15, row=(lane>>4)*4+r ----
    const int col = lane & 15;
    const int rbase = (lane >> 4) * 4;
    #pragma unroll
    for (int i = 0; i < 4; ++i)
        #pragma unroll
        for (int j = 0; j < 4; ++j) {
            const int rr = wm + i * 16 + rbase;
            const int cc = wn + j * 16 + col;
            #pragma unroll
            for (int r = 0; r < 4; ++r)
                Ct[(rr + r) * CT_STRIDE + cc] = f2b(acc[i][j][r]);
        }
    __syncthreads();

    // ---- consume this bin's tap entries (atomic-free) ----
    const size_t bin = (size_t)blockIdx.y * NB + blockIdx.x;
    const unsigned* __restrict__ cseg = cnts + bin * BPQ;
    const uint2* __restrict__ eseg = gent + bin * BPQ * SEG;

    const int seg = tid & 63;              // 4 threads cooperate per segment
    const unsigned c = min(cseg[seg], (unsigned)SEG);
    for (unsigned i = (unsigned)(tid >> 6); i < c; i += 4) {
        const uint2 e = eseg[seg * SEG + i];
        const int col0 = (int)(e.x & 127u);
        const int slot = (int)((e.x >> 7) & 3u);
        const int l    = (int)(e.x >> 9);
        const int r    = (l >> 7) & 127;   // query row within this q-block
        HWPack hw; hw.u = e.y;
        const int col1 = col0 + (col0 < 127 ? 1 : 0);
        const float v0 = b2f(Ct[r * CT_STRIDE + col0]);
        const float v1 = b2f(Ct[r * CT_STRIDE + col1]);
        const float o = (float)hw.h[0] * v0 + (float)hw.h[1] * v1;
        pp[(size_t)slot * L + l] = o;      // single-writer slot: plain store
    }
}

// ---------------- Phase 3: out = identity + (sum of 4 pp slots) / 16 ----------------
__global__ __launch_bounds__(256) void combine_kernel(
    const float* __restrict__ pp, const float* __restrict__ identity,
    float* __restrict__ out, int L)
{
    const int i = blockIdx.x * 256 + threadIdx.x;   // one float4 per thread
    if (i * 4 >= L) return;
    const float4 id = reinterpret_cast<const float4*>(identity)[i];
    const float4 a = reinterpret_cast<const float4*>(pp)[i];
    const float4 b = reinterpret_cast<const float4*>(pp + L)[i];
    const float4 c = reinterpret_cast<const float4*>(pp + 2 * (size_t)L)[i];
    const float4 d = reinterpret_cast<const float4*>(pp + 3 * (size_t)L)[i];
    float4 o;
    o.x = fmaf(a.x + b.x + c.x + d.x, 0.0625f, id.x);
    o.y = fmaf(a.y + b.y + c.y + d.y, 0.0625f, id.y);
    o.z = fmaf(a.z + b.z + c.z + d.z, 0.0625f, id.z);
    o.w = fmaf(a.w + b.w + c.w + d.w, 0.0625f, id.w);
    reinterpret_cast<float4*>(out)[i] = o;
}

// ---------------- Fallback (round-1 direct kernel) ----------------
__global__ __launch_bounds__(256) void uv_direct_kernel(
    const float* __restrict__ key, const float* __restrict__ value,
    const float* __restrict__ identity, const float* __restrict__ ref3d,
    const int* __restrict__ spatial, float* __restrict__ out)
{
    const int q = blockIdx.x;
    const int tid = threadIdx.x;
    const int lane = tid & 63;
    const int wave = tid >> 6;
    const int H = spatial[0], W = spatial[1];
    const int row4 = EMBED / 4;
    const float4 k4 = reinterpret_cast<const float4*>(key + (size_t)q * EMBED)[lane];
    const float4* __restrict__ v4 = reinterpret_cast<const float4*>(value);
    for (int d = wave; d < NUM_DEPTH; d += 4) {
        const int l = q * NUM_DEPTH + d;
        const float rx = ref3d[2 * l], ry = ref3d[2 * l + 1];
        const float px = rx * (float)W - 0.5f, py = ry * (float)H - 0.5f;
        const float x0f = floorf(px), y0f = floorf(py);
        const int ix0 = (int)x0f, iy0 = (int)y0f, ix1 = ix0 + 1, iy1 = iy0 + 1;
        const float wx1 = px - x0f, wx0 = 1.f - wx1, wy1 = py - y0f, wy0 = 1.f - wy1;
        float4 acc = make_float4(0.f, 0.f, 0.f, 0.f);
        #define TAP(IY, IX, WGT) \
            if ((IY) >= 0 && (IY) < H && (IX) >= 0 && (IX) < W) { \
                const float w_ = (WGT); \
                const float4 t = v4[(size_t)((IY) * W + (IX)) * row4 + lane]; \
                acc.x = fmaf(w_, t.x, acc.x); acc.y = fmaf(w_, t.y, acc.y); \
                acc.z = fmaf(w_, t.z, acc.z); acc.w = fmaf(w_, t.w, acc.w); }
        TAP(iy0, ix0, wy0 * wx0) TAP(iy0, ix1, wy0 * wx1)
        TAP(iy1, ix0, wy1 * wx0) TAP(iy1, ix1, wy1 * wx1)
        #undef TAP
        float partial = acc.x * k4.x + acc.y * k4.y + acc.z * k4.z + acc.w * k4.w;
        #pragma unroll
        for (int off = 32; off > 0; off >>= 1) partial += __shfl_xor(partial, off, 64);
        if (lane == 0) out[l] = fmaf(partial, 0.0625f, identity[l]);
    }
}

extern "C" void kernel_launch(void* const* d_in, const int* in_sizes, int n_in,
                              void* d_out, int out_size, void* d_ws, size_t ws_size,
                              hipStream_t stream) {
    // inputs: 0 query(unused) 1 key 2 value 3 identity 4 ref_3d 5 spatial 6 W_attn(unused) 7 b_attn(unused)
    const float* key      = (const float*)d_in[1];
    const float* value    = (const float*)d_in[2];
    const float* identity = (const float*)d_in[3];
    const float* ref3d    = (const float*)d_in[4];
    const int*   spatial  = (const int*)d_in[5];
    float* out = (float*)d_out;

    const int nq = in_sizes[3] / NUM_DEPTH;   // 4096 queries
    const int nv = in_sizes[1] / EMBED;       // 4096 pixels (= H*W)
    const int L  = nq * NUM_DEPTH;

    const int MB = nq >> 7, NB = nv >> 7;
    const size_t kb_bytes  = (size_t)nq * EMBED * sizeof(unsigned short);
    const size_t vb_bytes  = (size_t)nv * EMBED * sizeof(unsigned short);
    const size_t cnt_bytes = (size_t)MB * NB * BPQ * sizeof(unsigned);
    const size_t ent_bytes = (size_t)MB * NB * BPQ * SEG * sizeof(uint2);
    const size_t pp_bytes  = (size_t)4 * L * sizeof(float);
    const size_t need = kb_bytes + vb_bytes + cnt_bytes + ent_bytes + pp_bytes;

    if (ws_size < need || (nq % 128) || (nv % 128) || nv > 4096 || nq > 4096 || nq != nv) {
        uv_direct_kernel<<<nq, 256, 0, stream>>>(key, value, identity, ref3d, spatial, out);
        return;
    }

    unsigned short* kb = (unsigned short*)d_ws;
    unsigned short* vb = (unsigned short*)((char*)d_ws + kb_bytes);
    unsigned* cnts = (unsigned*)((char*)d_ws + kb_bytes + vb_bytes);
    uint2* gent = (uint2*)((char*)d_ws + kb_bytes + vb_bytes + cnt_bytes);
    float* pp = (float*)((char*)d_ws + kb_bytes + vb_bytes + cnt_bytes + ent_bytes);

    // Phase 1: convert key/value to bf16 + bin taps (weights precomputed) + zero pp
    const int n4 = nq * EMBED / 4;
    const int cvtBlocks = (n4 + 255) / 256;
    const int binBlocks = L / 256;
    prep_kernel<<<cvtBlocks + binBlocks, 256, 0, stream>>>(
        (const float4*)key, (const float4*)value, (ushort4*)kb, (ushort4*)vb,
        n4, cvtBlocks, ref3d, spatial, pp, cnts, gent, NB, nv, L);

    // Phase 2: tiled D = key.value^T with in-LDS atomic-free tap scatter
    dim3 grid(NB, MB);
    gemm_scatter<<<grid, 256, 0, stream>>>(kb, vb, pp, cnts, gent, NB, L);

    // Phase 3: combine partial sums with identity
    combine_kernel<<<L / 1024, 256, 0, stream>>>(pp, identity, out, L);
}

// Round 3
// 103.221 us; speedup vs baseline: 1.9819x; 1.0443x over previous
//
#include <hip/hip_runtime.h>

#define EMBED 256
#define NUM_DEPTH 128

typedef __attribute__((ext_vector_type(8))) short bf16x8;
typedef __attribute__((ext_vector_type(4))) float f32x4;

__device__ __forceinline__ unsigned short f2b(float f) {
    union { float f; unsigned u; } c; c.f = f;
    unsigned u = c.u;
    u += 0x7fffu + ((u >> 16) & 1u);   // RNE to bf16
    return (unsigned short)(u >> 16);
}
__device__ __forceinline__ float b2f(unsigned short h) {
    union { unsigned u; float f; } c; c.u = ((unsigned)h) << 16;
    return c.f;
}

// ---------------- Phase 1: fp32 -> bf16 conversion of key & value ----------------
__global__ __launch_bounds__(256) void cvt_kernel(
    const float4* __restrict__ key, const float4* __restrict__ val,
    ushort4* __restrict__ kb, ushort4* __restrict__ vb, int n4)
{
    int i = blockIdx.x * blockDim.x + threadIdx.x;
    if (i >= n4) return;
    float4 a = key[i];
    float4 b = val[i];
    kb[i] = make_ushort4(f2b(a.x), f2b(a.y), f2b(a.z), f2b(a.w));
    vb[i] = make_ushort4(f2b(b.x), f2b(b.y), f2b(b.z), f2b(b.w));
}

// ---------------- Phase 2: D[q][p] = sum_e key[q,e]*value[p,e]  (NT GEMM) --------
// Thin-K GEMM (K=256, only 8 K-steps) -> latency/barrier-bound, so optimize for
// occupancy not per-block work: 128x64 tile, 256 threads (4 waves 2x2), acc 4x2,
// 12 KB LDS, direct bf16 fragment stores (no C repack; lanes 0-15 cover one 32B
// sector so stores stay sector-complete). launch_bounds(256,6): ~24 waves/CU vs
// the previous 34.8KB-LDS version's 4 blocks/CU (38-42% measured occupancy).
__global__ __launch_bounds__(256, 6) void gemm_nt_bf16(
    const unsigned short* __restrict__ A,   // key bf16 [M][256]
    const unsigned short* __restrict__ B,   // value bf16 [N][256]
    unsigned short* __restrict__ D,         // [M][N] bf16
    int N, int NBl)
{
    __shared__ __align__(16) unsigned short As[128 * 32];  // 8 KB
    __shared__ __align__(16) unsigned short Bs[64 * 32];   // 4 KB

    // bijective XCD-aware remap (m204): contiguous grid chunk per XCD -> A-panels
    // stay resident in that XCD's L2.
    const int nwg = gridDim.x;
    const int xcd = blockIdx.x & 7;
    const int off = blockIdx.x >> 3;
    const int qch = nwg >> 3, rch = nwg & 7;
    const int wg = (xcd < rch ? xcd * (qch + 1) : rch * (qch + 1) + (xcd - rch) * qch) + off;

    const int m0 = (wg / NBl) * 128;
    const int n0 = (wg % NBl) * 64;
    const int tid  = threadIdx.x;
    const int lane = tid & 63;
    const int wave = tid >> 6;
    const int wm = (wave & 1) * 64;    // 2x2 wave grid over 128x64
    const int wn = (wave >> 1) * 32;

    f32x4 acc[4][2] = {};

    const int srow = lane >> 2;
    const int scol = (lane & 3) * 8;
    const int k8 = (lane >> 4) * 8;
    const int fm = lane & 15;

    for (int kt = 0; kt < EMBED; kt += 32) {
        #pragma unroll
        for (int t = 0; t < 2; ++t) {
            const int c = wave * 2 + t;                 // 8 sub-blocks of 16 rows -> 128
            const int row = c * 16 + srow;
            const unsigned short* ga = A + (size_t)(m0 + row) * EMBED + kt + scol;
            __builtin_amdgcn_global_load_lds(
                (const __attribute__((address_space(1))) void*)ga,
                (__attribute__((address_space(3))) void*)(As + c * 512), 16, 0, 0);
        }
        {
            const int c = wave;                          // 4 sub-blocks of 16 rows -> 64
            const int row = c * 16 + srow;
            const unsigned short* gb = B + (size_t)(n0 + row) * EMBED + kt + scol;
            __builtin_amdgcn_global_load_lds(
                (const __attribute__((address_space(1))) void*)gb,
                (__attribute__((address_space(3))) void*)(Bs + c * 512), 16, 0, 0);
        }
        __syncthreads();

        bf16x8 af[4], bfr[2];
        #pragma unroll
        for (int i = 0; i < 4; ++i)
            af[i]  = *(const bf16x8*)(As + (wm + i * 16 + fm) * 32 + k8);
        #pragma unroll
        for (int j = 0; j < 2; ++j)
            bfr[j] = *(const bf16x8*)(Bs + (wn + j * 16 + fm) * 32 + k8);
        #pragma unroll
        for (int i = 0; i < 4; ++i)
            #pragma unroll
            for (int j = 0; j < 2; ++j)
                acc[i][j] = __builtin_amdgcn_mfma_f32_16x16x32_bf16(af[i], bfr[j], acc[i][j], 0, 0, 0);
        __syncthreads();
    }

    // ---- direct fragment stores. C/D layout: col=lane&15, row=(lane>>4)*4+r ----
    const int col = lane & 15;
    const int rbase = (lane >> 4) * 4;
    #pragma unroll
    for (int i = 0; i < 4; ++i)
        #pragma unroll
        for (int j = 0; j < 2; ++j) {
            const int cc = n0 + wn + j * 16 + col;
            #pragma unroll
            for (int r = 0; r < 4; ++r)
                D[(size_t)(m0 + wm + i * 16 + rbase + r) * N + cc] = f2b(acc[i][j][r]);
        }
}

// ---------------- Phase 3: bilinear gather (LDS-staged D rows) + identity -------
// One block per 2 queries; stage both 8 KB D-rows into LDS coalesced, then each
// thread computes one output element with 4 ds_read taps.
__global__ __launch_bounds__(256) void gather_kernel(
    const unsigned short* __restrict__ D,   // [nq][nv] bf16
    const float* __restrict__ identity,     // [nq*128]
    const float* __restrict__ ref3d,        // [nq*128][2]
    const int*   __restrict__ spatial,      // {H, W}
    float* __restrict__ out, int nv)
{
    __shared__ unsigned short Ds[2 * 4096];  // 16 KB (nv <= 4096 guarded on host)

    const int q0 = blockIdx.x * 2;
    const int tid = threadIdx.x;

    // coalesced stage: 2*nv ushorts = 4*nv bytes
    const int4* src = (const int4*)(D + (size_t)q0 * nv);
    int4* dst = (int4*)Ds;
    const int nchunk = (2 * nv) / 8;
    for (int i = tid; i < nchunk; i += 256) dst[i] = src[i];
    __syncthreads();

    const int Hs = spatial[0], Ws = spatial[1];
    const int l = q0 * NUM_DEPTH + tid;      // 256 threads == 2 q * 128 d
    const int qi = tid >> 7;                  // 0 or 1

    const float2 r2 = reinterpret_cast<const float2*>(ref3d)[l];
    const float px = r2.x * (float)Ws - 0.5f;
    const float py = r2.y * (float)Hs - 0.5f;
    const float x0f = floorf(px), y0f = floorf(py);
    const int ix0 = (int)x0f, iy0 = (int)y0f;
    const int ix1 = ix0 + 1,  iy1 = iy0 + 1;
    const float wx1 = px - x0f, wx0 = 1.0f - wx1;
    const float wy1 = py - y0f, wy0 = 1.0f - wy1;
    const bool vx0 = (ix0 >= 0) & (ix0 < Ws);
    const bool vx1 = (ix1 >= 0) & (ix1 < Ws);

    const unsigned short* row = Ds + qi * nv;
    float acc = 0.f;
    if (iy0 >= 0 && iy0 < Hs) {
        if (vx0) acc = fmaf(wy0 * wx0, b2f(row[iy0 * Ws + ix0]), acc);
        if (vx1) acc = fmaf(wy0 * wx1, b2f(row[iy0 * Ws + ix1]), acc);
    }
    if (iy1 >= 0 && iy1 < Hs) {
        if (vx0) acc = fmaf(wy1 * wx0, b2f(row[iy1 * Ws + ix0]), acc);
        if (vx1) acc = fmaf(wy1 * wx1, b2f(row[iy1 * Ws + ix1]), acc);
    }
    out[l] = fmaf(acc, 0.0625f, identity[l]);  // 1/sqrt(256) = 1/16
}

// ---------------- Fallback (round-1 direct kernel) ----------------
__global__ __launch_bounds__(256) void uv_direct_kernel(
    const float* __restrict__ key, const float* __restrict__ value,
    const float* __restrict__ identity, const float* __restrict__ ref3d,
    const int* __restrict__ spatial, float* __restrict__ out)
{
    const int q = blockIdx.x;
    const int tid = threadIdx.x;
    const int lane = tid & 63;
    const int wave = tid >> 6;
    const int H = spatial[0], W = spatial[1];
    const int row4 = EMBED / 4;
    const float4 k4 = reinterpret_cast<const float4*>(key + (size_t)q * EMBED)[lane];
    const float4* __restrict__ v4 = reinterpret_cast<const float4*>(value);
    for (int d = wave; d < NUM_DEPTH; d += 4) {
        const int l = q * NUM_DEPTH + d;
        const float rx = ref3d[2 * l], ry = ref3d[2 * l + 1];
        const float px = rx * (float)W - 0.5f, py = ry * (float)H - 0.5f;
        const float x0f = floorf(px), y0f = floorf(py);
        const int ix0 = (int)x0f, iy0 = (int)y0f, ix1 = ix0 + 1, iy1 = iy0 + 1;
        const float wx1 = px - x0f, wx0 = 1.f - wx1, wy1 = py - y0f, wy0 = 1.f - wy1;
        float4 acc = make_float4(0.f, 0.f, 0.f, 0.f);
        #define TAP(IY, IX, WGT) \
            if ((IY) >= 0 && (IY) < H && (IX) >= 0 && (IX) < W) { \
                const float w_ = (WGT); \
                const float4 t = v4[(size_t)((IY) * W + (IX)) * row4 + lane]; \
                acc.x = fmaf(w_, t.x, acc.x); acc.y = fmaf(w_, t.y, acc.y); \
                acc.z = fmaf(w_, t.z, acc.z); acc.w = fmaf(w_, t.w, acc.w); }
        TAP(iy0, ix0, wy0 * wx0) TAP(iy0, ix1, wy0 * wx1)
        TAP(iy1, ix0, wy1 * wx0) TAP(iy1, ix1, wy1 * wx1)
        #undef TAP
        float partial = acc.x * k4.x + acc.y * k4.y + acc.z * k4.z + acc.w * k4.w;
        #pragma unroll
        for (int off = 32; off > 0; off >>= 1) partial += __shfl_xor(partial, off, 64);
        if (lane == 0) out[l] = fmaf(partial, 0.0625f, identity[l]);
    }
}

extern "C" void kernel_launch(void* const* d_in, const int* in_sizes, int n_in,
                              void* d_out, int out_size, void* d_ws, size_t ws_size,
                              hipStream_t stream) {
    // inputs: 0 query(unused) 1 key 2 value 3 identity 4 ref_3d 5 spatial 6 W_attn(unused) 7 b_attn(unused)
    const float* key      = (const float*)d_in[1];
    const float* value    = (const float*)d_in[2];
    const float* identity = (const float*)d_in[3];
    const float* ref3d    = (const float*)d_in[4];
    const int*   spatial  = (const int*)d_in[5];
    float* out = (float*)d_out;

    const int nq = in_sizes[3] / NUM_DEPTH;   // 4096 queries
    const int nv = in_sizes[1] / EMBED;       // 4096 pixels (= H*W)

    const size_t d_bytes  = (size_t)nq * nv * sizeof(unsigned short);
    const size_t kb_bytes = (size_t)nq * EMBED * sizeof(unsigned short);
    const size_t vb_bytes = (size_t)nv * EMBED * sizeof(unsigned short);
    const size_t need = d_bytes + kb_bytes + vb_bytes;

    if (ws_size < need || (nq % 128) || (nv % 128) || nv > 4096 || (nq % 2) || nq != nv) {
        uv_direct_kernel<<<nq, 256, 0, stream>>>(key, value, identity, ref3d, spatial, out);
        return;
    }

    unsigned short* D  = (unsigned short*)d_ws;
    unsigned short* kb = (unsigned short*)((char*)d_ws + d_bytes);
    unsigned short* vb = (unsigned short*)((char*)d_ws + d_bytes + kb_bytes);

    // Phase 1: convert key & value to bf16
    const int n4 = nq * EMBED / 4;
    cvt_kernel<<<(n4 + 255) / 256, 256, 0, stream>>>(
        (const float4*)key, (const float4*)value, (ushort4*)kb, (ushort4*)vb, n4);

    // Phase 2: D = key . value^T  (128x64 tiles, high occupancy)
    const int NBl = nv / 64;
    const int nwg = (nq / 128) * NBl;
    gemm_nt_bf16<<<nwg, 256, 0, stream>>>(kb, vb, D, nv, NBl);

    // Phase 3: bilinear gather + identity (2 queries per block)
    gather_kernel<<<nq / 2, 256, 0, stream>>>(D, identity, ref3d, spatial, out, nv);
}